// Round 7
// baseline (597.101 us; speedup 1.0000x reference)
//
#include <hip/hip_runtime.h>
#include <math.h>

// ---------------------------------------------------------------------------
// HardVectorQuantizer on MI355X — round 7: plain-f16 MFMA + provable rescue
// R6: hi/lo-split MFMA argmin 240 µs (MfmaUtil 41.5%), total 436 µs, absmax 0.
// R7: pass-1 = plain f16 GEMM (1 MFMA per dot, not 3; half LDS -> 4 blk/CU).
//     Error bound (rigorous): dist_err <= szz_t*see_k*2^-9*1.033 (+0.02 slack).
//     Pass-1 emits all codes within (min + E_X + E_max + slack) of the running
//     global/block min into per-token candidate lists (true argmin provably
//     included). Rescue kernel prunes by the same bound, recomputes EXACT fp32
//     distances for survivors, picks lexicographic (dist, idx) min, and does
//     the gather/residual/sse/counts in the same kernel. Overflow -> full
//     exact scan (always correct).
//  K0 prep:    eh=f16(emb), zh=f16(z), zz/ee, szz/see=sqrt norms, semax
//  K1 argmin:  128x128 f16 MFMA -> packed atomicMin + candidate emission
//  K2 rescue:  prune + exact fp32 argmin + gather + sse + counts
//  K3 stats:   scalars
// ---------------------------------------------------------------------------

#define DDIM 512
#define MTOK 8192
#define KCODE 8192
#define NOUTE (MTOK * DDIM)

#define BM 128
#define BN 128
#define BK 32
#define NK (DDIM / BK)        // 16
#define NCAND 128
#define MARGIN_SLACK 0.02f

// ws layout (bytes)
#define OFF_EH 0u
#define OFF_ZH (OFF_EH + (unsigned)KCODE * DDIM * 2u)      //  8 MB
#define OFF_EE (OFF_ZH + (unsigned)MTOK * DDIM * 2u)       // 16 MB
#define OFF_ZZ (OFF_EE + KCODE * 4u)
#define OFF_SEE (OFF_ZZ + MTOK * 4u)
#define OFF_SZZ (OFF_SEE + KCODE * 4u)
#define OFF_PACKED (OFF_SZZ + MTOK * 4u)                   // 8192 x u64
#define OFF_CAND (OFF_PACKED + MTOK * 8u)                  // 8192 x 128 x u64
#define OFF_CCNT (OFF_CAND + (unsigned)MTOK * NCAND * 8u)  // zero-block start
#define OFF_COUNTS (OFF_CCNT + MTOK * 4u)
#define OFF_SSE (OFF_COUNTS + KCODE * 4u)
#define OFF_SEMAX (OFF_SSE + 8u)
#define ZERO_BYTES (MTOK * 4u + KCODE * 4u + 8u + 4u)

typedef _Float16 half8 __attribute__((ext_vector_type(8)));
typedef float f32x16 __attribute__((ext_vector_type(16)));

// monotone float <-> u32 order-preserving map
__device__ __forceinline__ unsigned enc_f(float x) {
  unsigned u = __float_as_uint(x);
  return u ^ (((unsigned)((int)u >> 31)) | 0x80000000u);
}
__device__ __forceinline__ float dec_f(unsigned y) {
  return __uint_as_float((y & 0x80000000u) ? (y ^ 0x80000000u) : ~y);
}

// ---------------------- K0: f16 cast + norms + sqrt-norms + semax, one pass
__global__ __launch_bounds__(256) void prep_kernel(const float* __restrict__ z,
                                                   const float* __restrict__ emb,
                                                   _Float16* __restrict__ eh,
                                                   _Float16* __restrict__ zh,
                                                   float* __restrict__ zz,
                                                   float* __restrict__ ee,
                                                   float* __restrict__ see,
                                                   float* __restrict__ szz,
                                                   unsigned* __restrict__ semax) {
  const int row = blockIdx.x * 4 + (threadIdx.x >> 6);
  const int lane = threadIdx.x & 63;
  const float* src;
  _Float16* dh;
  float *nrm, *sq;
  int r;
  bool isEmb;
  if (row < KCODE) { src = emb + (size_t)row * DDIM; dh = eh; nrm = ee; sq = see; r = row; isEmb = true; }
  else { src = z + (size_t)(row - KCODE) * DDIM; dh = zh; nrm = zz; sq = szz; r = row - KCODE; isEmb = false; }
  const float4* s4 = reinterpret_cast<const float4*>(src);
  const float4 v0 = s4[lane * 2 + 0];
  const float4 v1 = s4[lane * 2 + 1];
  const float vv[8] = {v0.x, v0.y, v0.z, v0.w, v1.x, v1.y, v1.z, v1.w};
  half8 hv;
  float s = 0.f;
#pragma unroll
  for (int i = 0; i < 8; ++i) {
    s = fmaf(vv[i], vv[i], s);
    hv[i] = (_Float16)vv[i];
  }
  *reinterpret_cast<half8*>(dh + (size_t)r * DDIM + lane * 8) = hv;
#pragma unroll
  for (int off = 32; off > 0; off >>= 1) s += __shfl_down(s, off, 64);
  if (lane == 0) {
    nrm[r] = s;
    const float q = sqrtf(s);
    sq[r] = q;
    if (isEmb) atomicMax(semax, enc_f(q));
  }
}

// stage one 4 KB half-tile (64 rows x 64 B) as 4 x 1 KB DMA writes.
// LDS dest linear (lane*16); XOR swizzle (slot s of row r holds chunk
// s ^ ((r>>1)&3)) applied by pre-swizzling the per-lane GLOBAL address.
__device__ __forceinline__ void stage_half(const char* gb, char* lb) {
#pragma unroll
  for (int i = 0; i < 4; ++i)
    __builtin_amdgcn_global_load_lds(
        (const __attribute__((address_space(1))) unsigned int*)(gb + i * 16384),
        (__attribute__((address_space(3))) unsigned int*)(lb + i * 1024), 16, 0, 0);
}

// ------------------------------- K1: f16 MFMA GEMM + argmin + cand emission
// LDS per buffer: {Ah, Bh} each [128][32] f16 = 8 KB -> 16 KB; dbuf 32 KB.
// Wave w stages half-tile w (A lo/hi rows, B lo/hi rows). Read side swizzle
// verbatim from the bitwise-verified R4/R6 kernels.
__global__ __launch_bounds__(256) void argmin_mfma_kernel(
    const _Float16* __restrict__ eh, const _Float16* __restrict__ zh,
    const float* __restrict__ zz, const float* __restrict__ ee,
    const float* __restrict__ see, const float* __restrict__ szz,
    const unsigned* __restrict__ semaxp,
    unsigned long long* __restrict__ packed,
    int* __restrict__ ccnt, unsigned long long* __restrict__ cand) {
  __shared__ __align__(16) unsigned char smem[32768];

  const int tid = threadIdx.x;
  const int l = tid & 63;
  const int w = tid >> 6;
  const int wr = w >> 1;           // code-half
  const int wc = w & 1;            // token-half
  const int codeBase = blockIdx.x * BM;
  const int tokBase = blockIdx.y * BN;

  // staging: wave w covers (w<2 ? A : B), rows (w&1)*64 .. +63
  const _Float16* tileSrc = (w < 2) ? eh + (size_t)codeBase * DDIM
                                    : zh + (size_t)tokBase * DDIM;
  const int cS = (l & 3) ^ ((l >> 3) & 3);
  const char* gsrc = (const char*)tileSrc + (size_t)((w & 1) * 64 + (l >> 2)) * 1024 + cS * 16;
  char* ldsHalf = (char*)smem + (w >> 1) * 8192 + (w & 1) * 4096;

  // fragment read offsets (swizzle verbatim R4/R6)
  const int keyR = (l >> 1) & 3;
  const int rowA = wr * 64 + (l & 31);
  const int rowB = wc * 64 + (l & 31);
  const int aH = rowA * 64;
  const int bH = 8192 + rowB * 64;

  f32x16 hh[2][2];
#pragma unroll
  for (int mt = 0; mt < 2; ++mt)
#pragma unroll
    for (int nt = 0; nt < 2; ++nt)
#pragma unroll
      for (int i = 0; i < 16; ++i) hh[mt][nt][i] = 0.f;

#define LDF(off) (*(const half8*)((const char*)smem + (off)))
#define MFMA(a, b, c) __builtin_amdgcn_mfma_f32_32x32x16_f16((a), (b), (c), 0, 0, 0)

  stage_half(gsrc, ldsHalf);
  asm volatile("s_waitcnt vmcnt(0)" ::: "memory");
  __syncthreads();

#pragma unroll 1
  for (int c = 0; c < NK; ++c) {
    const int cur = c & 1;
    if (c + 1 < NK)
      stage_half(gsrc + (size_t)(c + 1) * 64, ldsHalf + (cur ^ 1) * 16384);
    const int bo = cur * 16384;
#pragma unroll
    for (int ks = 0; ks < 2; ++ks) {
      const int cs = ((ks * 2 + (l >> 5)) ^ keyR) << 4;
      const half8 a0 = LDF(bo + aH + cs);
      const half8 a1 = LDF(bo + aH + 2048 + cs);
      const half8 b0 = LDF(bo + bH + cs);
      const half8 b1 = LDF(bo + bH + 2048 + cs);
      hh[0][0] = MFMA(a0, b0, hh[0][0]);
      hh[0][1] = MFMA(a0, b1, hh[0][1]);
      hh[1][0] = MFMA(a1, b0, hh[1][0]);
      hh[1][1] = MFMA(a1, b1, hh[1][1]);
    }
    asm volatile("s_waitcnt vmcnt(0)" ::: "memory");
    __syncthreads();
  }

  // ---- epilogue: approx dist = (zz - 2*dot) + ee
  float* eeS = (float*)smem;                  // 128
  float* seeS = (float*)(smem + 512);         // 128
  float* pd = (float*)(smem + 1024);          // 256
  int* pi = (int*)(smem + 2048);              // 256
  float* lim = (float*)(smem + 3072);         // 128
  if (tid < BM) { eeS[tid] = ee[codeBase + tid]; seeS[tid] = see[codeBase + tid]; }
  __syncthreads();

  float ztt[2], szt[2];
#pragma unroll
  for (int nt = 0; nt < 2; ++nt) {
    const int lt = wc * 64 + nt * 32 + (l & 31);
    ztt[nt] = zz[tokBase + lt];
    szt[nt] = szz[tokBase + lt];
    float bd = INFINITY;
    int bi = 0x7fffffff;
#pragma unroll
    for (int mt = 0; mt < 2; ++mt)
#pragma unroll
      for (int r = 0; r < 16; ++r) {
        const int rowL = wr * 64 + mt * 32 + (r & 3) + ((r >> 2) << 3) + ((l >> 5) << 2);
        const float dist = (ztt[nt] - 2.0f * hh[mt][nt][r]) + eeS[rowL];
        const int code = codeBase + rowL;
        if (dist < bd || (dist == bd && code < bi)) { bd = dist; bi = code; }
      }
    const float od = __shfl_xor(bd, 32, 64);
    const int oi = __shfl_xor(bi, 32, 64);
    if (od < bd || (od == bd && oi < bi)) { bd = od; bi = oi; }
    if (l < 32) { pd[w * 64 + nt * 32 + l] = bd; pi[w * 64 + nt * 32 + l] = bi; }
  }
  __syncthreads();
  if (tid < BN) {
    const int wcc = tid >> 6, rest = tid & 63;
    float da = pd[wcc * 64 + rest];
    int ia = pi[wcc * 64 + rest];
    const float db = pd[(2 + wcc) * 64 + rest];
    const int ib = pi[(2 + wcc) * 64 + rest];
    if (db < da || (db == da && ib < ia)) { da = db; ia = ib; }
    const unsigned long long key = ((unsigned long long)enc_f(da) << 32) | (unsigned)ia;
    atomicMin(&packed[tokBase + tid], key);
    const unsigned long long curk = packed[tokBase + tid];  // >= final M: safe
    lim[tid] = fminf(da, dec_f((unsigned)(curk >> 32)));
  }
  __syncthreads();

  // ---- candidate emission: d <= lim + E_X + E_max + slack guarantees the
  // true argmin is emitted by its own block (proof: triangle on approx bound).
  const float semaxv = dec_f(*semaxp);
#pragma unroll
  for (int nt = 0; nt < 2; ++nt) {
    const int lt = wc * 64 + nt * 32 + (l & 31);
    const float L = lim[lt];
    const int tokG = tokBase + lt;
#pragma unroll
    for (int mt = 0; mt < 2; ++mt)
#pragma unroll
      for (int r = 0; r < 16; ++r) {
        const int rowL = wr * 64 + mt * 32 + (r & 3) + ((r >> 2) << 3) + ((l >> 5) << 2);
        const float dist = (ztt[nt] - 2.0f * hh[mt][nt][r]) + eeS[rowL];
        const float mar = (seeS[rowL] + semaxv) * szt[nt] * (1.0625f / 512.0f) + MARGIN_SLACK;
        if (dist <= L + mar) {
          const int pos = atomicAdd(&ccnt[tokG], 1);
          if (pos < NCAND)
            cand[(size_t)tokG * NCAND + pos] =
                ((unsigned long long)enc_f(dist) << 32) | (unsigned)(codeBase + rowL);
        }
      }
  }
#undef LDF
#undef MFMA
}

// -------------- K2: prune + exact fp32 argmin + gather + sse + counts
__global__ __launch_bounds__(256) void rescue_gather_kernel(
    const float* __restrict__ z, const float* __restrict__ emb,
    const float* __restrict__ zz, const float* __restrict__ ee,
    const float* __restrict__ see, const float* __restrict__ szz,
    const unsigned* __restrict__ semaxp,
    const unsigned long long* __restrict__ packed,
    const int* __restrict__ ccnt, const unsigned long long* __restrict__ cand,
    const unsigned char* __restrict__ mask,
    float* __restrict__ out, float* __restrict__ counts, double* __restrict__ sse) {
  const int t = blockIdx.x * 4 + (threadIdx.x >> 6);  // one wave per token
  const int l = threadIdx.x & 63;
  const float zz_t = zz[t];
  const float szz_t = szz[t];
  const float semaxv = dec_f(*semaxp);
  const float M = dec_f((unsigned)(packed[t] >> 32));
  const float* zp = z + (size_t)t * DDIM;
  float zv[8];
#pragma unroll
  for (int j = 0; j < 8; ++j) zv[j] = zp[j * 64 + l];

  const int n = ccnt[t];
  float bd = INFINITY;
  int bi = 0x7fffffff;

  if (n <= NCAND) {
    for (int base = 0; base < n; base += 64) {
      const int c = base + l;
      const bool act = c < n;
      const unsigned long long key = act ? cand[(size_t)t * NCAND + c] : ~0ull;
      const int idx = (int)(key & 0xffffffffu);
      bool keep = false;
      if (act) {
        const float dap = dec_f((unsigned)(key >> 32));
        const float mar = (see[idx] + semaxv) * szz_t * (1.0625f / 512.0f) + MARGIN_SLACK;
        keep = (dap <= M + mar);
      }
      unsigned long long surv = __ballot(keep);
      while (surv) {
        const int b = __ffsll(surv) - 1;
        surv &= surv - 1;
        const int ci = __shfl(idx, b, 64);
        const float* ep = emb + (size_t)ci * DDIM;
        float dot = 0.f;
#pragma unroll
        for (int j = 0; j < 8; ++j) dot = fmaf(zv[j], ep[j * 64 + l], dot);
#pragma unroll
        for (int off = 32; off > 0; off >>= 1) dot += __shfl_xor(dot, off, 64);
        const float dx = (zz_t - 2.0f * dot) + ee[ci];
        if (dx < bd || (dx == bd && ci < bi)) { bd = dx; bi = ci; }
      }
    }
  } else {
    // overflow fallback: exact scan over all codes (correct, never expected)
    for (int k = 0; k < KCODE; ++k) {
      const float* ep = emb + (size_t)k * DDIM;
      float dot = 0.f;
#pragma unroll
      for (int j = 0; j < 8; ++j) dot = fmaf(zv[j], ep[j * 64 + l], dot);
#pragma unroll
      for (int off = 32; off > 0; off >>= 1) dot += __shfl_xor(dot, off, 64);
      const float dx = (zz_t - 2.0f * dot) + ee[k];
      if (dx < bd || (dx == bd && k < bi)) { bd = dx; bi = k; }
    }
  }

  // gather + residual + sse + counts (all lanes agree on bi)
  const float* ep = emb + (size_t)bi * DDIM;
  float* rp = out + (size_t)t * DDIM;
  float* qp = out + (size_t)NOUTE + 1 + (size_t)t * DDIM;
  float s = 0.f;
#pragma unroll
  for (int j = 0; j < 8; ++j) {
    const int d = j * 64 + l;
    const float ev = ep[d];
    const float r = zv[j] - ev;
    rp[d] = r;
    qp[d] = ev;
    s = fmaf(r, r, s);
  }
#pragma unroll
  for (int off = 32; off > 0; off >>= 1) s += __shfl_down(s, off, 64);
  if (l == 0) {
    const float wgt = mask[t] ? 0.0f : 1.0f;
    atomicAdd(sse, (double)s * (double)wgt);
    atomicAdd(&counts[bi], wgt);
  }
}

// ------------------------------------------------- K3: scalars
__global__ __launch_bounds__(1024) void stats_kernel(const float* __restrict__ counts,
                                                     const unsigned char* __restrict__ mask,
                                                     const double* __restrict__ sse,
                                                     float* __restrict__ out) {
  __shared__ double sd[1024];
  __shared__ int si[1024];
  const int tid = threadIdx.x;

  int nv = 0;
  for (int i = tid; i < MTOK; i += 1024) nv += (mask[i] ? 0 : 1);
  si[tid] = nv;
  __syncthreads();
#pragma unroll
  for (int s = 512; s > 0; s >>= 1) {
    if (tid < s) si[tid] += si[tid + s];
    __syncthreads();
  }
  const int n_valid = si[0];
  __syncthreads();

  double ct = 0.0;
  for (int k = tid; k < KCODE; k += 1024) ct += (double)counts[k];
  sd[tid] = ct;
  __syncthreads();
#pragma unroll
  for (int s = 512; s > 0; s >>= 1) {
    if (tid < s) sd[tid] += sd[tid + s];
    __syncthreads();
  }
  const float total = fmaxf((float)sd[0], 1.0f);
  __syncthreads();

  double ent = 0.0;
  int used = 0;
  for (int k = tid; k < KCODE; k += 1024) {
    const float c = counts[k];
    if (c > 0.f) ++used;
    const float p = c / total;
    ent += (double)(p * logf(p + 1e-10f));
  }
  sd[tid] = ent;
  si[tid] = used;
  __syncthreads();
#pragma unroll
  for (int s = 512; s > 0; s >>= 1) {
    if (tid < s) { sd[tid] += sd[tid + s]; si[tid] += si[tid + s]; }
    __syncthreads();
  }
  if (tid == 0) {
    const float entropy = -(float)sd[0];
    const float perp = expf(entropy);
    const int usedc = si[0];
    const int nv1 = n_valid > 1 ? n_valid : 1;
    const float denom = (float)(nv1 * DDIM);
    const float L = (float)sse[0] / denom;
    out[NOUTE] = L + 0.25f * L;
    out[2 * NOUTE + 1] = perp;
    out[2 * NOUTE + 2] = (float)usedc;
    out[2 * NOUTE + 3] = (float)usedc / (float)KCODE;
  }
}

// ---------------------------------------------------------------------------
extern "C" void kernel_launch(void* const* d_in, const int* in_sizes, int n_in,
                              void* d_out, int out_size, void* d_ws, size_t ws_size,
                              hipStream_t stream) {
  const float* z = (const float*)d_in[0];
  const unsigned char* mask = (const unsigned char*)d_in[1];
  const float* emb = (const float*)d_in[2];
  float* out = (float*)d_out;
  char* ws = (char*)d_ws;

  _Float16* eh = (_Float16*)(ws + OFF_EH);
  _Float16* zh = (_Float16*)(ws + OFF_ZH);
  float* ee = (float*)(ws + OFF_EE);
  float* zz = (float*)(ws + OFF_ZZ);
  float* see = (float*)(ws + OFF_SEE);
  float* szz = (float*)(ws + OFF_SZZ);
  unsigned long long* packed = (unsigned long long*)(ws + OFF_PACKED);
  unsigned long long* cand = (unsigned long long*)(ws + OFF_CAND);
  int* ccnt = (int*)(ws + OFF_CCNT);
  float* counts = (float*)(ws + OFF_COUNTS);
  double* sse = (double*)(ws + OFF_SSE);
  unsigned* semax = (unsigned*)(ws + OFF_SEMAX);

  hipMemsetAsync(ws + OFF_PACKED, 0xFF, MTOK * 8u, stream);
  hipMemsetAsync(ws + OFF_CCNT, 0, ZERO_BYTES, stream);  // ccnt+counts+sse+semax

  hipLaunchKernelGGL(prep_kernel, dim3((KCODE + MTOK) / 4), dim3(256), 0, stream,
                     z, emb, eh, zh, zz, ee, see, szz, semax);
  hipLaunchKernelGGL(argmin_mfma_kernel, dim3(KCODE / BM, MTOK / BN), dim3(256), 0, stream,
                     eh, zh, zz, ee, see, szz, semax, packed, ccnt, cand);
  hipLaunchKernelGGL(rescue_gather_kernel, dim3(MTOK / 4), dim3(256), 0, stream,
                     z, emb, zz, ee, see, szz, semax, packed, ccnt, cand, mask,
                     out, counts, sse);
  hipLaunchKernelGGL(stats_kernel, dim3(1), dim3(1024), 0, stream,
                     counts, mask, sse, out);
}

// Round 8
// 401.703 us; speedup vs baseline: 1.4864x; 1.4864x over previous
//
#include <hip/hip_runtime.h>
#include <math.h>

// ---------------------------------------------------------------------------
// HardVectorQuantizer on MI355X — round 8: f16 pass-1 + bitmask exact rescue
// R6 (best): hi/lo MFMA 240 µs — LDS-read-bound (m134 model: 4:1 LDS:MFMA,
//   matches MfmaUtil 41%). R7: f16+candidate-lists regressed (emission atomics
//   + VGPR 140 occupancy cliff) BUT proved margin+rescue correct (absmax 0.0).
// R8: f16 pass-1 (1/3 MFMA, 1/2 LDS bytes of R6) with ATOMIC-FREE epilogue:
//   per-(tok,block) packed blockmin u64 (token-major) + 128-bit candidate
//   mask (d~ <= blockmin + 2*marU, marU = semax*szz_t*2.125/512 + 0.02).
//   Proof: d~(k*) <= d(k*)+mar <= M+2marU <= blockmin_b+2marU, and k*'s
//   block's min <= M+2marU -> suspicious-block + mask walk finds k* always.
//   Rescue: u64-min of 64 partials, exact fp32 dots on flagged codes only,
//   lexicographic (dist,idx) min, then gather/residual/sse/counts fused.
//  K0 prep:   eh=f16(emb), zh=f16(z), ee/zz, szz, semax
//  K1 pass1:  128x128 f16 MFMA -> part[tok][64] u64 + mask[tok][64][2] u64
//  K2 rescue: exact argmin + gather + sse + counts
//  K3 stats:  scalars
// ---------------------------------------------------------------------------

#define DDIM 512
#define MTOK 8192
#define KCODE 8192
#define NOUTE (MTOK * DDIM)

#define BM 128
#define BN 128
#define BK 32
#define NK (DDIM / BK)        // 16
#define NCB (KCODE / BM)      // 64 code blocks
#define MAR_C (2.125f / 512.0f)   // 2*1.0625/512 (R7-verified per-code margin x2/semax-bound)
#define MAR_S 0.02f               // slack per mar term

// ws layout (bytes)
#define OFF_EH 0u
#define OFF_ZH (OFF_EH + (unsigned)KCODE * DDIM * 2u)          //  8388608
#define OFF_EE (OFF_ZH + (unsigned)MTOK * DDIM * 2u)           // 16777216
#define OFF_ZZ (OFF_EE + KCODE * 4u)
#define OFF_SZZ (OFF_ZZ + MTOK * 4u)
#define OFF_PART (OFF_SZZ + MTOK * 4u)                         // tok-major u64 [MTOK][64]
#define OFF_MASK (OFF_PART + (unsigned)MTOK * NCB * 8u)        // u64 [MTOK][64][2]
#define OFF_COUNTS (OFF_MASK + (unsigned)MTOK * NCB * 2u * 8u)
#define OFF_SSE (OFF_COUNTS + KCODE * 4u)
#define OFF_SEMAX (OFF_SSE + 8u)
#define ZERO_BYTES (KCODE * 4u + 8u + 4u)

typedef _Float16 half8 __attribute__((ext_vector_type(8)));
typedef float f32x16 __attribute__((ext_vector_type(16)));
typedef unsigned long long u64;

// monotone float <-> u32 order-preserving map
__device__ __forceinline__ unsigned enc_f(float x) {
  unsigned u = __float_as_uint(x);
  return u ^ (((unsigned)((int)u >> 31)) | 0x80000000u);
}
__device__ __forceinline__ float dec_f(unsigned y) {
  return __uint_as_float((y & 0x80000000u) ? (y ^ 0x80000000u) : ~y);
}

// ---------------------- K0: f16 cast + norms + sqrt-norm + semax
__global__ __launch_bounds__(256) void prep_kernel(const float* __restrict__ z,
                                                   const float* __restrict__ emb,
                                                   _Float16* __restrict__ eh,
                                                   _Float16* __restrict__ zh,
                                                   float* __restrict__ zz,
                                                   float* __restrict__ ee,
                                                   float* __restrict__ szz,
                                                   unsigned* __restrict__ semax) {
  const int row = blockIdx.x * 4 + (threadIdx.x >> 6);
  const int lane = threadIdx.x & 63;
  const float* src;
  _Float16* dh;
  float* nrm;
  int r;
  bool isEmb;
  if (row < KCODE) { src = emb + (size_t)row * DDIM; dh = eh; nrm = ee; r = row; isEmb = true; }
  else { src = z + (size_t)(row - KCODE) * DDIM; dh = zh; nrm = zz; r = row - KCODE; isEmb = false; }
  const float4* s4 = reinterpret_cast<const float4*>(src);
  const float4 v0 = s4[lane * 2 + 0];
  const float4 v1 = s4[lane * 2 + 1];
  const float vv[8] = {v0.x, v0.y, v0.z, v0.w, v1.x, v1.y, v1.z, v1.w};
  half8 hv;
  float s = 0.f;
#pragma unroll
  for (int i = 0; i < 8; ++i) {
    s = fmaf(vv[i], vv[i], s);
    hv[i] = (_Float16)vv[i];
  }
  *reinterpret_cast<half8*>(dh + (size_t)r * DDIM + lane * 8) = hv;
#pragma unroll
  for (int off = 32; off > 0; off >>= 1) s += __shfl_down(s, off, 64);
  if (lane == 0) {
    nrm[r] = s;
    const float q = sqrtf(s);
    if (isEmb) atomicMax(semax, enc_f(q));
    else szz[r] = q;
  }
}

// stage one 4 KB half-tile (64 rows x 64 B) as 4 x 1 KB DMA writes (R7-verified).
__device__ __forceinline__ void stage_half(const char* gb, char* lb) {
#pragma unroll
  for (int i = 0; i < 4; ++i)
    __builtin_amdgcn_global_load_lds(
        (const __attribute__((address_space(1))) unsigned int*)(gb + i * 16384),
        (__attribute__((address_space(3))) unsigned int*)(lb + i * 1024), 16, 0, 0);
}

// ------------------------------- K1: f16 MFMA GEMM -> blockmin + mask
__global__ __launch_bounds__(256) void pass1_kernel(
    const _Float16* __restrict__ eh, const _Float16* __restrict__ zh,
    const float* __restrict__ zz, const float* __restrict__ ee,
    const float* __restrict__ szz, const unsigned* __restrict__ semaxp,
    u64* __restrict__ part, u64* __restrict__ maskG) {
  __shared__ __align__(16) unsigned char smem[32768];

  const int tid = threadIdx.x;
  const int l = tid & 63;
  const int w = tid >> 6;
  const int wr = w >> 1;           // code-half
  const int wc = w & 1;            // token-half
  const int codeBase = blockIdx.x * BM;
  const int tokBase = blockIdx.y * BN;

  // staging (verbatim R7, verified): wave w covers (w<2 ? A : B), rows (w&1)*64
  const _Float16* tileSrc = (w < 2) ? eh + (size_t)codeBase * DDIM
                                    : zh + (size_t)tokBase * DDIM;
  const int cS = (l & 3) ^ ((l >> 3) & 3);
  const char* gsrc = (const char*)tileSrc + (size_t)((w & 1) * 64 + (l >> 2)) * 1024 + cS * 16;
  char* ldsHalf = (char*)smem + (w >> 1) * 8192 + (w & 1) * 4096;

  // fragment read offsets (swizzle verbatim R4/R6/R7)
  const int keyR = (l >> 1) & 3;
  const int rowA = wr * 64 + (l & 31);
  const int rowB = wc * 64 + (l & 31);
  const int aH = rowA * 64;
  const int bH = 8192 + rowB * 64;

  f32x16 hh[2][2];
#pragma unroll
  for (int mt = 0; mt < 2; ++mt)
#pragma unroll
    for (int nt = 0; nt < 2; ++nt)
#pragma unroll
      for (int i = 0; i < 16; ++i) hh[mt][nt][i] = 0.f;

#define LDF(off) (*(const half8*)((const char*)smem + (off)))
#define MFMA(a, b, c) __builtin_amdgcn_mfma_f32_32x32x16_f16((a), (b), (c), 0, 0, 0)

  stage_half(gsrc, ldsHalf);
  asm volatile("s_waitcnt vmcnt(0)" ::: "memory");
  __syncthreads();

#pragma unroll 1
  for (int c = 0; c < NK; ++c) {
    const int cur = c & 1;
    if (c + 1 < NK)
      stage_half(gsrc + (size_t)(c + 1) * 64, ldsHalf + (cur ^ 1) * 16384);
    const int bo = cur * 16384;
#pragma unroll
    for (int ks = 0; ks < 2; ++ks) {
      const int cs = ((ks * 2 + (l >> 5)) ^ keyR) << 4;
      const half8 a0 = LDF(bo + aH + cs);
      const half8 a1 = LDF(bo + aH + 2048 + cs);
      const half8 b0 = LDF(bo + bH + cs);
      const half8 b1 = LDF(bo + bH + 2048 + cs);
      hh[0][0] = MFMA(a0, b0, hh[0][0]);
      hh[0][1] = MFMA(a0, b1, hh[0][1]);
      hh[1][0] = MFMA(a1, b0, hh[1][0]);
      hh[1][1] = MFMA(a1, b1, hh[1][1]);
    }
    asm volatile("s_waitcnt vmcnt(0)" ::: "memory");
    __syncthreads();
  }

  // ---- epilogue (atomic-free). LDS reuse: pkS[2][128] u64 @0 (2KB),
  // bmS[128] u64 @2048 (1KB), eeS[128] f32 @4096.
  u64* pkS = (u64*)smem;
  u64* bmS = (u64*)(smem + 2048);
  float* eeS = (float*)(smem + 4096);
  if (tid < BM) eeS[tid] = ee[codeBase + tid];
  __syncthreads();

  float ztt[2], szt[2];
  // stage A: per-token block-min (packed u64 lexicographic)
#pragma unroll
  for (int nt = 0; nt < 2; ++nt) {
    const int lt = wc * 64 + nt * 32 + (l & 31);
    ztt[nt] = zz[tokBase + lt];
    szt[nt] = szz[tokBase + lt];
    u64 bk = ~0ull;
#pragma unroll
    for (int mt = 0; mt < 2; ++mt)
#pragma unroll
      for (int r = 0; r < 16; ++r) {
        const int rowL = wr * 64 + mt * 32 + (r & 3) + ((r >> 2) << 3) + ((l >> 5) << 2);
        const float dist = (ztt[nt] - 2.0f * hh[mt][nt][r]) + eeS[rowL];
        const u64 key = ((u64)enc_f(dist) << 32) | (unsigned)(codeBase + rowL);
        if (key < bk) bk = key;
      }
    const u64 ok = __shfl_xor(bk, 32, 64);
    if (ok < bk) bk = ok;
    if (l < 32) pkS[wr * 128 + wc * 64 + nt * 32 + l] = bk;
  }
  __syncthreads();
  if (tid < BN) {
    const u64 a = pkS[tid], b = pkS[128 + tid];
    const u64 m = a < b ? a : b;
    bmS[tid] = m;
    part[(size_t)(tokBase + tid) * NCB + blockIdx.x] = m;
  }
  __syncthreads();

  // stage B: candidate mask — d~ <= blockmin + 2*marU
  const float semaxv = dec_f(*semaxp);
#pragma unroll
  for (int nt = 0; nt < 2; ++nt) {
    const int lt = wc * 64 + nt * 32 + (l & 31);
    const float thr = dec_f((unsigned)(bmS[lt] >> 32))
                    + semaxv * szt[nt] * MAR_C + 2.0f * MAR_S;
    u64 m64 = 0;
#pragma unroll
    for (int mt = 0; mt < 2; ++mt)
#pragma unroll
      for (int r = 0; r < 16; ++r) {
        const int rloc = mt * 32 + (r & 3) + ((r >> 2) << 3) + ((l >> 5) << 2);
        const float dist = (ztt[nt] - 2.0f * hh[mt][nt][r]) + eeS[wr * 64 + rloc];
        if (dist <= thr) m64 |= (1ull << rloc);
      }
    m64 |= __shfl_xor(m64, 32, 64);
    if (l < 32)
      maskG[(size_t)(tokBase + lt) * (NCB * 2) + blockIdx.x * 2 + wr] = m64;
  }
#undef LDF
#undef MFMA
}

// -------------- K2: exact rescue + gather + sse + counts (one wave/token)
__global__ __launch_bounds__(256) void rescue_gather_kernel(
    const float* __restrict__ z, const float* __restrict__ emb,
    const float* __restrict__ zz, const float* __restrict__ ee,
    const float* __restrict__ szz, const unsigned* __restrict__ semaxp,
    const u64* __restrict__ part, const u64* __restrict__ maskG,
    const unsigned char* __restrict__ mask,
    float* __restrict__ out, float* __restrict__ counts, double* __restrict__ sse) {
  const int t = blockIdx.x * 4 + (threadIdx.x >> 6);
  const int l = threadIdx.x & 63;
  const float zz_t = zz[t];
  const float* zp = z + (size_t)t * DDIM;
  float zv[8];
#pragma unroll
  for (int j = 0; j < 8; ++j) zv[j] = zp[j * 64 + l];

  // wave-min over the 64 block partials (lane l holds block l) — coalesced
  const u64 pk = part[(size_t)t * NCB + l];
  u64 M = pk;
#pragma unroll
  for (int off = 32; off > 0; off >>= 1) {
    const u64 o = __shfl_xor(M, off, 64);
    if (o < M) M = o;
  }
  const float thr = dec_f((unsigned)(M >> 32))
                  + dec_f(*semaxp) * szz[t] * MAR_C + 2.0f * MAR_S;
  u64 sb = __ballot(dec_f((unsigned)(pk >> 32)) <= thr);

  float bd = INFINITY;
  int bi = 0x7fffffff;
  while (sb) {
    const int b = __ffsll(sb) - 1;
    sb &= sb - 1;
#pragma unroll
    for (int h = 0; h < 2; ++h) {
      u64 m64 = maskG[(size_t)t * (NCB * 2) + b * 2 + h];  // uniform load
      while (m64) {
        const int bit = __ffsll(m64) - 1;
        m64 &= m64 - 1;
        const int code = b * BM + h * 64 + bit;
        const float* ep = emb + (size_t)code * DDIM;
        float dot = 0.f;
#pragma unroll
        for (int j = 0; j < 8; ++j) dot = fmaf(zv[j], ep[j * 64 + l], dot);
#pragma unroll
        for (int off = 32; off > 0; off >>= 1) dot += __shfl_xor(dot, off, 64);
        const float dx = (zz_t - 2.0f * dot) + ee[code];
        if (dx < bd || (dx == bd && code < bi)) { bd = dx; bi = code; }
      }
    }
  }

  // gather + residual + sse + counts (all lanes agree on bi)
  const float* ep = emb + (size_t)bi * DDIM;
  float* rp = out + (size_t)t * DDIM;
  float* qp = out + (size_t)NOUTE + 1 + (size_t)t * DDIM;
  float s = 0.f;
#pragma unroll
  for (int j = 0; j < 8; ++j) {
    const int d = j * 64 + l;
    const float ev = ep[d];
    const float r = zv[j] - ev;
    rp[d] = r;
    qp[d] = ev;
    s = fmaf(r, r, s);
  }
#pragma unroll
  for (int off = 32; off > 0; off >>= 1) s += __shfl_down(s, off, 64);
  if (l == 0) {
    const float wgt = mask[t] ? 0.0f : 1.0f;
    atomicAdd(sse, (double)s * (double)wgt);
    atomicAdd(&counts[bi], wgt);
  }
}

// ------------------------------------------------- K3: scalars
__global__ __launch_bounds__(1024) void stats_kernel(const float* __restrict__ counts,
                                                     const unsigned char* __restrict__ mask,
                                                     const double* __restrict__ sse,
                                                     float* __restrict__ out) {
  __shared__ double sd[1024];
  __shared__ int si[1024];
  const int tid = threadIdx.x;

  int nv = 0;
  for (int i = tid; i < MTOK; i += 1024) nv += (mask[i] ? 0 : 1);
  si[tid] = nv;
  __syncthreads();
#pragma unroll
  for (int s = 512; s > 0; s >>= 1) {
    if (tid < s) si[tid] += si[tid + s];
    __syncthreads();
  }
  const int n_valid = si[0];
  __syncthreads();

  double ct = 0.0;
  for (int k = tid; k < KCODE; k += 1024) ct += (double)counts[k];
  sd[tid] = ct;
  __syncthreads();
#pragma unroll
  for (int s = 512; s > 0; s >>= 1) {
    if (tid < s) sd[tid] += sd[tid + s];
    __syncthreads();
  }
  const float total = fmaxf((float)sd[0], 1.0f);
  __syncthreads();

  double ent = 0.0;
  int used = 0;
  for (int k = tid; k < KCODE; k += 1024) {
    const float c = counts[k];
    if (c > 0.f) ++used;
    const float p = c / total;
    ent += (double)(p * logf(p + 1e-10f));
  }
  sd[tid] = ent;
  si[tid] = used;
  __syncthreads();
#pragma unroll
  for (int s = 512; s > 0; s >>= 1) {
    if (tid < s) { sd[tid] += sd[tid + s]; si[tid] += si[tid + s]; }
    __syncthreads();
  }
  if (tid == 0) {
    const float entropy = -(float)sd[0];
    const float perp = expf(entropy);
    const int usedc = si[0];
    const int nv1 = n_valid > 1 ? n_valid : 1;
    const float denom = (float)(nv1 * DDIM);
    const float L = (float)sse[0] / denom;
    out[NOUTE] = L + 0.25f * L;
    out[2 * NOUTE + 1] = perp;
    out[2 * NOUTE + 2] = (float)usedc;
    out[2 * NOUTE + 3] = (float)usedc / (float)KCODE;
  }
}

// ---------------------------------------------------------------------------
extern "C" void kernel_launch(void* const* d_in, const int* in_sizes, int n_in,
                              void* d_out, int out_size, void* d_ws, size_t ws_size,
                              hipStream_t stream) {
  const float* z = (const float*)d_in[0];
  const unsigned char* maskIn = (const unsigned char*)d_in[1];
  const float* emb = (const float*)d_in[2];
  float* out = (float*)d_out;
  char* ws = (char*)d_ws;

  _Float16* eh = (_Float16*)(ws + OFF_EH);
  _Float16* zh = (_Float16*)(ws + OFF_ZH);
  float* ee = (float*)(ws + OFF_EE);
  float* zz = (float*)(ws + OFF_ZZ);
  float* szz = (float*)(ws + OFF_SZZ);
  u64* part = (u64*)(ws + OFF_PART);
  u64* maskG = (u64*)(ws + OFF_MASK);
  float* counts = (float*)(ws + OFF_COUNTS);
  double* sse = (double*)(ws + OFF_SSE);
  unsigned* semax = (unsigned*)(ws + OFF_SEMAX);

  // part/maskG are fully overwritten by pass1 — no init needed.
  hipMemsetAsync(ws + OFF_COUNTS, 0, ZERO_BYTES, stream);  // counts+sse+semax

  hipLaunchKernelGGL(prep_kernel, dim3((KCODE + MTOK) / 4), dim3(256), 0, stream,
                     z, emb, eh, zh, zz, ee, szz, semax);
  hipLaunchKernelGGL(pass1_kernel, dim3(KCODE / BM, MTOK / BN), dim3(256), 0, stream,
                     eh, zh, zz, ee, szz, semax, part, maskG);
  hipLaunchKernelGGL(rescue_gather_kernel, dim3(MTOK / 4), dim3(256), 0, stream,
                     z, emb, zz, ee, szz, semax, part, maskG, maskIn,
                     out, counts, sse);
  hipLaunchKernelGGL(stats_kernel, dim3(1), dim3(1024), 0, stream,
                     counts, maskIn, sse, out);
}